// Round 5
// baseline (97.262 us; speedup 1.0000x reference)
//
#include <hip/hip_runtime.h>
#include <math.h>

// Problem constants (fixed by setup_inputs)
constexpr int Bc = 256, Sc = 1024, Dc = 32, Kc = 512;
constexpr int ST = 256;                      // s-rows per main block
constexpr float LOG2E    = 1.4426950408889634f;
constexpr float LN2      = 0.6931471805599453f;
constexpr float LOG_NORM = 29.40603306051f;  // D * 0.5 * log(2*pi)

typedef __attribute__((ext_vector_type(8))) short          bf16x8;
typedef __attribute__((ext_vector_type(8))) unsigned short u16x8;
typedef __attribute__((ext_vector_type(4))) unsigned short u16x4;
typedef __attribute__((ext_vector_type(4))) float          f32x4;

#if __has_builtin(__builtin_amdgcn_exp2f)
#define EXP2F(v) __builtin_amdgcn_exp2f(v)
#else
#define EXP2F(v) exp2f(v)
#endif
#if __has_builtin(__builtin_amdgcn_logf)
#define LOG2F(v) __builtin_amdgcn_logf(v)
#else
#define LOG2F(v) log2f(v)
#endif

__device__ __forceinline__ unsigned short f2bf(float f) {
    unsigned u = __float_as_uint(f);
    u += 0x7fff + ((u >> 16) & 1);           // round-to-nearest-even
    return (unsigned short)(u >> 16);
}

// XOR-swizzled LDS offset (ushort units): row stride 32 bf16 (64B),
// chunk = 16B octet 0..3, XORed with (row>>1)&3. Measured 0 conflicts (R2/R4).
__device__ __forceinline__ int swz(int row, int chunk) {
    return row * 32 + ((chunk ^ ((row >> 1) & 3)) << 3);
}

// ---------------- pre-kernel ----------------
// grid(Bc), block(256). Coalesced flat means read; chunk sq-sums via LDS.
// Block 0 additionally writes bf16 means. wbuf[b*K+k] = exp2((l-lse-0.5*m2)*log2e)
__global__ __launch_bounds__(256)
void gm_prep(const float* __restrict__ logits, const float* __restrict__ means,
             float* __restrict__ wbuf, unsigned short* __restrict__ mbf)
{
    __shared__ float csum[4096];   // 16 KB: per-float4-chunk sum of squares
    __shared__ float red[8];
    const int tid  = threadIdx.x;
    const int lane = tid & 63;
    const int wid  = tid >> 6;
    const int b    = blockIdx.x;

    // flat coalesced read of means (4096 float4 chunks), square-reduce each
    const float4* m4 = (const float4*)means;
    #pragma unroll
    for (int j = 0; j < 16; ++j) {
        const int i = tid + j * 256;
        float4 v = m4[i];
        csum[i] = v.x*v.x + v.y*v.y + v.z*v.z + v.w*v.w;
        if (b == 0) {           // convert to bf16 once, coalesced ushort4 stores
            u16x4 pk;
            pk[0] = f2bf(v.x); pk[1] = f2bf(v.y); pk[2] = f2bf(v.z); pk[3] = f2bf(v.w);
            *(u16x4*)&mbf[i * 4] = pk;
        }
    }

    // logsumexp over logits[b,:]
    const float l0 = logits[b * Kc + tid];
    const float l1 = logits[b * Kc + tid + 256];
    float mx = fmaxf(l0, l1);
    #pragma unroll
    for (int off = 32; off >= 1; off >>= 1) mx = fmaxf(mx, __shfl_xor(mx, off));
    if (lane == 0) red[wid] = mx;
    __syncthreads();
    mx = fmaxf(fmaxf(red[0], red[1]), fmaxf(red[2], red[3]));
    float sm = EXP2F((l0 - mx) * LOG2E) + EXP2F((l1 - mx) * LOG2E);
    #pragma unroll
    for (int off = 32; off >= 1; off >>= 1) sm += __shfl_xor(sm, off);
    if (lane == 0) red[4 + wid] = sm;
    __syncthreads();
    sm = red[4] + red[5] + red[6] + red[7];
    const float lse = mx + LN2 * LOG2F(sm);

    // m2 for k = tid, tid+256 from LDS chunk sums (8 adds each)
    #pragma unroll
    for (int rr = 0; rr < 2; ++rr) {
        const int k = tid + rr * 256;
        const float* cs = &csum[k * 8];
        float m2 = ((cs[0] + cs[1]) + (cs[2] + cs[3]))
                 + ((cs[4] + cs[5]) + (cs[6] + cs[7]));
        const float lg = (rr == 0) ? l0 : l1;
        wbuf[(size_t)b * Kc + k] = EXP2F((lg - lse - 0.5f * m2) * LOG2E);
    }
}

// ---------------- main kernel ----------------
// grid(Bc * Sc/ST) = 1024 blocks (exactly 4/CU), 256 threads = 4 waves.
// Wave owns 64 s-rows (four 16-row subtiles sharing each B-fragment).
__global__ __launch_bounds__(256, 4)
void gm_main(const float* __restrict__ x, const float* __restrict__ wbuf,
             const unsigned short* __restrict__ mbf, float* __restrict__ out)
{
    __shared__ unsigned short mlds[Kc * 32];  // 32 KB bf16 means, XOR-swizzled
    __shared__ float wlds[Kc];                //  2 KB mixture weights
    __shared__ float x2p[ST];                 //  1 KB per-row sum(x^2)

    const int tid  = threadIdx.x;
    const int lane = tid & 63;
    const int wid  = tid >> 6;
    const int b    = blockIdx.x >> 2;
    const int s0   = (blockIdx.x & 3) * ST;
    const int q    = lane >> 4;               // k-octet of contraction dim
    const int ln   = lane & 15;
    const int rw   = wid * 64;

    // stage means (32 KB vector copy into swizzled layout) + weights
    {
        const u16x8* src = (const u16x8*)mbf;
        #pragma unroll
        for (int j = 0; j < 8; ++j) {
            const int c = tid + j * 256;       // 16B-chunk index 0..2047
            *(u16x8*)&mlds[swz(c >> 2, c & 3)] = src[c];
        }
        wlds[tid]       = wbuf[(size_t)b * Kc + tid];
        wlds[tid + 256] = wbuf[(size_t)b * Kc + tid + 256];
    }

    // x A-fragments direct from global; 4 subtiles (rows rw+16t+ln)
    bf16x8 a[4];
    #pragma unroll
    for (int t = 0; t < 4; ++t) {
        const int row = rw + 16 * t + ln;
        const float4* xp = (const float4*)(x + ((size_t)b * Sc + s0 + row) * Dc) + q * 2;
        float4 v0 = xp[0], v1 = xp[1];
        a[t][0]=(short)f2bf(v0.x*LOG2E); a[t][1]=(short)f2bf(v0.y*LOG2E);
        a[t][2]=(short)f2bf(v0.z*LOG2E); a[t][3]=(short)f2bf(v0.w*LOG2E);
        a[t][4]=(short)f2bf(v1.x*LOG2E); a[t][5]=(short)f2bf(v1.y*LOG2E);
        a[t][6]=(short)f2bf(v1.z*LOG2E); a[t][7]=(short)f2bf(v1.w*LOG2E);
        float p = v0.x*v0.x + v0.y*v0.y + v0.z*v0.z + v0.w*v0.w
                + v1.x*v1.x + v1.y*v1.y + v1.z*v1.z + v1.w*v1.w;
        p += __shfl_xor(p, 16); p += __shfl_xor(p, 32);
        if (q == 0) x2p[row] = p;
    }
    __syncthreads();

    const f32x4 zero = {0.f, 0.f, 0.f, 0.f};
    float acc[4][4] = {};

    #pragma unroll 4
    for (int kt = 0; kt < 32; ++kt) {
        const int krow = kt * 16 + ln;
        const bf16x8 bfr = *(const bf16x8*)&mlds[swz(krow, q)];
        const float  wv  = wlds[krow];        // 16 consecutive floats, bcast over q
        f32x4 d0 = __builtin_amdgcn_mfma_f32_16x16x32_bf16(a[0], bfr, zero, 0, 0, 0);
        f32x4 d1 = __builtin_amdgcn_mfma_f32_16x16x32_bf16(a[1], bfr, zero, 0, 0, 0);
        f32x4 d2 = __builtin_amdgcn_mfma_f32_16x16x32_bf16(a[2], bfr, zero, 0, 0, 0);
        f32x4 d3 = __builtin_amdgcn_mfma_f32_16x16x32_bf16(a[3], bfr, zero, 0, 0, 0);
        #pragma unroll
        for (int r = 0; r < 4; ++r) {
            acc[0][r] = fmaf(wv, EXP2F(d0[r]), acc[0][r]);
            acc[1][r] = fmaf(wv, EXP2F(d1[r]), acc[1][r]);
            acc[2][r] = fmaf(wv, EXP2F(d2[r]), acc[2][r]);
            acc[3][r] = fmaf(wv, EXP2F(d3[r]), acc[3][r]);
        }
    }

    // reduce over the 16 k-columns (low-4 lane bits), then write
    #pragma unroll
    for (int t = 0; t < 4; ++t) {
        #pragma unroll
        for (int r = 0; r < 4; ++r) {
            float v = acc[t][r];
            v += __shfl_xor(v, 1); v += __shfl_xor(v, 2);
            v += __shfl_xor(v, 4); v += __shfl_xor(v, 8);
            if (ln == 0) {
                const int row = rw + 16 * t + q * 4 + r;   // C/D row = quad*4+reg
                out[(size_t)b * Sc + s0 + row] =
                    0.5f * x2p[row] + LOG_NORM - LN2 * LOG2F(v);
            }
        }
    }
}

extern "C" void kernel_launch(void* const* d_in, const int* in_sizes, int n_in,
                              void* d_out, int out_size, void* d_ws, size_t ws_size,
                              hipStream_t stream) {
    const float* x      = (const float*)d_in[0];
    const float* logits = (const float*)d_in[1];
    const float* means  = (const float*)d_in[2];
    float* out = (float*)d_out;
    (void)in_sizes; (void)n_in; (void)out_size; (void)ws_size;

    unsigned short* mbf  = (unsigned short*)d_ws;              // 32 KB
    float*          wbuf = (float*)((char*)d_ws + 32768);      // 512 KB

    hipLaunchKernelGGL(gm_prep, dim3(Bc), dim3(256), 0, stream,
                       logits, means, wbuf, mbf);
    hipLaunchKernelGGL(gm_main, dim3(Bc * (Sc / ST)), dim3(256), 0, stream,
                       x, wbuf, mbf, out);
}

// Round 6
// 94.655 us; speedup vs baseline: 1.0275x; 1.0275x over previous
//
#include <hip/hip_runtime.h>
#include <math.h>

// Problem constants (fixed by setup_inputs)
constexpr int Bc = 256, Sc = 1024, Dc = 32, Kc = 512;
constexpr int ST = 128;                      // s-rows per main block (R4 best)
constexpr float LOG2E    = 1.4426950408889634f;
constexpr float LN2      = 0.6931471805599453f;
constexpr float LOG_NORM = 29.40603306051f;  // D * 0.5 * log(2*pi)

typedef __attribute__((ext_vector_type(8))) short          bf16x8;
typedef __attribute__((ext_vector_type(8))) unsigned short u16x8;
typedef __attribute__((ext_vector_type(4))) float          f32x4;

#if __has_builtin(__builtin_amdgcn_exp2f)
#define EXP2F(v) __builtin_amdgcn_exp2f(v)
#else
#define EXP2F(v) exp2f(v)
#endif
#if __has_builtin(__builtin_amdgcn_logf)
#define LOG2F(v) __builtin_amdgcn_logf(v)
#else
#define LOG2F(v) log2f(v)
#endif

__device__ __forceinline__ unsigned short f2bf(float f) {
    unsigned u = __float_as_uint(f);
    u += 0x7fff + ((u >> 16) & 1);           // round-to-nearest-even
    return (unsigned short)(u >> 16);
}

// XOR-swizzled LDS offset (ushort units): row stride 32 bf16 (64B),
// chunk = 16B octet 0..3, XORed with (row>>1)&3. Measured 0 conflicts (R2/R4).
__device__ __forceinline__ int swz(int row, int chunk) {
    return row * 32 + ((chunk ^ ((row >> 1) & 3)) << 3);
}

// ---------------- tiny prep: means->bf16 + m2buf[512] ----------------
// grid(64) x 256: one element per thread, coalesced; 32-lane shfl reduce per row.
__global__ __launch_bounds__(256)
void gm_m2bf(const float* __restrict__ means,
             unsigned short* __restrict__ mbf, float* __restrict__ m2buf)
{
    const int i    = blockIdx.x * 256 + threadIdx.x;   // 0..16383
    const int lane = threadIdx.x & 63;
    const float v  = means[i];
    mbf[i] = f2bf(v);
    float sq = v * v;
    #pragma unroll
    for (int off = 1; off <= 16; off <<= 1) sq += __shfl_xor(sq, off);
    if ((lane & 31) == 0) m2buf[i >> 5] = sq;          // row = i/32
}

// ---------------- main kernel ----------------
// grid(Bc * Sc/ST) = 2048 blocks, 256 threads = 4 waves; wave owns 32 s-rows.
// Weights computed in-block WITHOUT lse (folded into epilogue):
//   acc = sum_k 2^((l_k - 0.5*m2_k)*log2e) * 2^(x.mu_k*log2e)
//   nll = 0.5*x^2 + LOG_NORM + lse - ln2*log2(acc)
__global__ __launch_bounds__(256)
void gm_main(const float* __restrict__ x, const float* __restrict__ logits,
             const float* __restrict__ m2buf, const unsigned short* __restrict__ mbf,
             float* __restrict__ out)
{
    __shared__ unsigned short mlds[Kc * 32];  // 32 KB bf16 means, XOR-swizzled
    __shared__ float wlds[Kc];                //  2 KB unnormalized weights
    __shared__ float x2p[ST];                 //  per-row sum(x^2)
    __shared__ float red[8];

    const int tid  = threadIdx.x;
    const int lane = tid & 63;
    const int wid  = tid >> 6;
    const int b    = blockIdx.x >> 3;
    const int s0   = (blockIdx.x & 7) * ST;
    const int q    = lane >> 4;               // k-octet of contraction dim
    const int ln   = lane & 15;
    const int rw   = wid * 32;

    // stage means: 32 KB coalesced vector copy into swizzled layout
    {
        const u16x8* src = (const u16x8*)mbf;
        #pragma unroll
        for (int j = 0; j < 8; ++j) {
            const int c = tid + j * 256;       // 16B-chunk index 0..2047
            *(u16x8*)&mlds[swz(c >> 2, c & 3)] = src[c];
        }
    }

    // in-block weights + lse over logits[b,:]
    const float l0 = logits[b * Kc + tid];
    const float l1 = logits[b * Kc + tid + 256];
    wlds[tid]       = EXP2F((l0 - 0.5f * m2buf[tid])       * LOG2E);
    wlds[tid + 256] = EXP2F((l1 - 0.5f * m2buf[tid + 256]) * LOG2E);

    float mx = fmaxf(l0, l1);
    #pragma unroll
    for (int off = 32; off >= 1; off >>= 1) mx = fmaxf(mx, __shfl_xor(mx, off));
    if (lane == 0) red[wid] = mx;

    // x A-fragments direct from global (row fully consumed by the 4 q-lanes)
    const int row0 = rw + ln, row1 = row0 + 16;
    const float4* xp0 = (const float4*)(x + ((size_t)b * Sc + s0 + row0) * Dc) + q * 2;
    const float4* xp1 = (const float4*)(x + ((size_t)b * Sc + s0 + row1) * Dc) + q * 2;
    float4 v0 = xp0[0], v1 = xp0[1];
    float4 u0 = xp1[0], u1 = xp1[1];

    bf16x8 a0, a1;
    a0[0]=(short)f2bf(v0.x*LOG2E); a0[1]=(short)f2bf(v0.y*LOG2E);
    a0[2]=(short)f2bf(v0.z*LOG2E); a0[3]=(short)f2bf(v0.w*LOG2E);
    a0[4]=(short)f2bf(v1.x*LOG2E); a0[5]=(short)f2bf(v1.y*LOG2E);
    a0[6]=(short)f2bf(v1.z*LOG2E); a0[7]=(short)f2bf(v1.w*LOG2E);
    a1[0]=(short)f2bf(u0.x*LOG2E); a1[1]=(short)f2bf(u0.y*LOG2E);
    a1[2]=(short)f2bf(u0.z*LOG2E); a1[3]=(short)f2bf(u0.w*LOG2E);
    a1[4]=(short)f2bf(u1.x*LOG2E); a1[5]=(short)f2bf(u1.y*LOG2E);
    a1[6]=(short)f2bf(u1.z*LOG2E); a1[7]=(short)f2bf(u1.w*LOG2E);

    float p0 = v0.x*v0.x + v0.y*v0.y + v0.z*v0.z + v0.w*v0.w
             + v1.x*v1.x + v1.y*v1.y + v1.z*v1.z + v1.w*v1.w;
    float p1 = u0.x*u0.x + u0.y*u0.y + u0.z*u0.z + u0.w*u0.w
             + u1.x*u1.x + u1.y*u1.y + u1.z*u1.z + u1.w*u1.w;
    p0 += __shfl_xor(p0, 16); p0 += __shfl_xor(p0, 32);
    p1 += __shfl_xor(p1, 16); p1 += __shfl_xor(p1, 32);
    if (q == 0) { x2p[row0] = p0; x2p[row1] = p1; }
    __syncthreads();

    // finish lse (max across waves was parked in red[0..3])
    const float mxb = fmaxf(fmaxf(red[0], red[1]), fmaxf(red[2], red[3]));
    float sm = EXP2F((l0 - mxb) * LOG2E) + EXP2F((l1 - mxb) * LOG2E);
    #pragma unroll
    for (int off = 32; off >= 1; off >>= 1) sm += __shfl_xor(sm, off);
    if (lane == 0) red[4 + wid] = sm;

    const f32x4 zero = {0.f, 0.f, 0.f, 0.f};
    float acc0[4] = {0.f, 0.f, 0.f, 0.f};
    float acc1[4] = {0.f, 0.f, 0.f, 0.f};

    #pragma unroll 8
    for (int kt = 0; kt < 32; ++kt) {
        const int krow = kt * 16 + ln;
        const bf16x8 bfr = *(const bf16x8*)&mlds[swz(krow, q)];
        const float  wv  = wlds[krow];        // 16 consecutive floats, bcast over q
        f32x4 d0 = __builtin_amdgcn_mfma_f32_16x16x32_bf16(a0, bfr, zero, 0, 0, 0);
        f32x4 d1 = __builtin_amdgcn_mfma_f32_16x16x32_bf16(a1, bfr, zero, 0, 0, 0);
        #pragma unroll
        for (int r = 0; r < 4; ++r) {
            acc0[r] = fmaf(wv, EXP2F(d0[r]), acc0[r]);
            acc1[r] = fmaf(wv, EXP2F(d1[r]), acc1[r]);
        }
    }
    __syncthreads();                          // red[4..7] ready
    const float lse = mxb + LN2 * LOG2F(red[4] + red[5] + red[6] + red[7]);
    const float base = LOG_NORM + lse;

    // reduce over the 16 k-columns (low-4 lane bits), then write
    #pragma unroll
    for (int r = 0; r < 4; ++r) {
        float s0v = acc0[r], s1v = acc1[r];
        s0v += __shfl_xor(s0v, 1); s0v += __shfl_xor(s0v, 2);
        s0v += __shfl_xor(s0v, 4); s0v += __shfl_xor(s0v, 8);
        s1v += __shfl_xor(s1v, 1); s1v += __shfl_xor(s1v, 2);
        s1v += __shfl_xor(s1v, 4); s1v += __shfl_xor(s1v, 8);
        if (ln == 0) {
            const int r0 = rw + q * 4 + r;       // C/D row = quad*4 + reg
            const int r1 = r0 + 16;
            out[(size_t)b * Sc + s0 + r0] = 0.5f * x2p[r0] + base - LN2 * LOG2F(s0v);
            out[(size_t)b * Sc + s0 + r1] = 0.5f * x2p[r1] + base - LN2 * LOG2F(s1v);
        }
    }
}

extern "C" void kernel_launch(void* const* d_in, const int* in_sizes, int n_in,
                              void* d_out, int out_size, void* d_ws, size_t ws_size,
                              hipStream_t stream) {
    const float* x      = (const float*)d_in[0];
    const float* logits = (const float*)d_in[1];
    const float* means  = (const float*)d_in[2];
    float* out = (float*)d_out;
    (void)in_sizes; (void)n_in; (void)out_size; (void)ws_size;

    unsigned short* mbf   = (unsigned short*)d_ws;             // 32 KB
    float*          m2buf = (float*)((char*)d_ws + 32768);     //  2 KB

    hipLaunchKernelGGL(gm_m2bf, dim3(64), dim3(256), 0, stream, means, mbf, m2buf);
    hipLaunchKernelGGL(gm_main, dim3(Bc * (Sc / ST)), dim3(256), 0, stream,
                       x, logits, m2buf, mbf, out);
}

// Round 8
// 90.018 us; speedup vs baseline: 1.0805x; 1.0515x over previous
//
#include <hip/hip_runtime.h>
#include <math.h>

// Problem constants (fixed by setup_inputs)
constexpr int Bc = 256, Sc = 1024, Dc = 32, Kc = 512;
constexpr int ST = 128;                      // s-rows per main block
constexpr float LOG2E    = 1.4426950408889634f;
constexpr float LN2      = 0.6931471805599453f;
constexpr float LOG_NORM = 29.40603306051f;  // D * 0.5 * log(2*pi)

typedef __attribute__((ext_vector_type(4))) float f32x4;

#if __has_builtin(__builtin_amdgcn_exp2f)
#define EXP2F(v) __builtin_amdgcn_exp2f(v)
#else
#define EXP2F(v) exp2f(v)
#endif
#if __has_builtin(__builtin_amdgcn_logf)
#define LOG2F(v) __builtin_amdgcn_logf(v)
#else
#define LOG2F(v) log2f(v)
#endif

// pack 2 f32 -> 2 e4m3 bytes; word_sel must be a compile-time constant.
template <bool HI>
__device__ __forceinline__ int pkfp8(float a, float b, int old) {
    return __builtin_amdgcn_cvt_pk_fp8_f32(a, b, old, HI);
}

// Swizzled LDS byte offset for fp8 means: row = k (32 B), chunk = 8B octet 0..3
// XORed with (row>>2)&3  ->  each q-group covers all 32 banks once (2-way total).
__device__ __forceinline__ int swz8(int row, int chunk) {
    return row * 32 + ((chunk ^ ((row >> 2) & 3)) << 3);
}

// ---------------- tiny prep: means -> e4m3 + m2buf[512] ----------------
// grid(32) x 256; thread owns 2 consecutive floats (coalesced 8B reads).
__global__ __launch_bounds__(256)
void gm_m2f8(const float* __restrict__ means,
             unsigned short* __restrict__ mf8, float* __restrict__ m2buf)
{
    const int t  = blockIdx.x * 256 + threadIdx.x;   // 0..8191 (pairs)
    const float v0 = means[2 * t];
    const float v1 = means[2 * t + 1];
    mf8[t] = (unsigned short)(pkfp8<false>(v0, v1, 0) & 0xffff);
    float sq = v0 * v0 + v1 * v1;
    #pragma unroll
    for (int off = 1; off <= 8; off <<= 1) sq += __shfl_xor(sq, off);
    if ((threadIdx.x & 15) == 0) m2buf[t >> 4] = sq;   // 16 pair-threads per row
}

// ---------------- main kernel ----------------
// grid(2048), 256 threads = 4 waves; wave owns 32 s-rows (2 x 16-row subtiles).
//   acc = sum_k 2^((l_k-0.5*m2_k)*log2e) * 2^((x*log2e).mu_k)
//   nll = 0.5*x^2 + LOG_NORM + lse - ln2*log2(acc)
__global__ __launch_bounds__(256, 6)
void gm_main(const float* __restrict__ x, const float* __restrict__ logits,
             const float* __restrict__ m2buf, const unsigned short* __restrict__ mf8,
             float* __restrict__ out)
{
    __shared__ unsigned char mlds[Kc * 32];   // 16 KB e4m3 means, swizzled
    __shared__ float wlds[Kc];                //  2 KB unnormalized weights
    __shared__ float x2p[ST];                 // 0.5 KB per-row sum(x^2)
    __shared__ float red[8];

    const int tid  = threadIdx.x;
    const int lane = tid & 63;
    const int wid  = tid >> 6;
    const int b    = blockIdx.x >> 3;
    const int s0   = (blockIdx.x & 7) * ST;
    const int q    = lane >> 4;               // k-octet of contraction dim
    const int ln   = lane & 15;
    const int rw   = wid * 32;

    // stage means: 16 KB coalesced copy (8B chunks) into swizzled layout
    {
        const unsigned long long* src = (const unsigned long long*)mf8;
        #pragma unroll
        for (int j = 0; j < 8; ++j) {
            const int c = tid + j * 256;       // 8B-chunk index 0..2047
            *(unsigned long long*)&mlds[swz8(c >> 2, c & 3)] = src[c];
        }
    }

    // in-block unnormalized weights + start of lse
    const float l0 = logits[b * Kc + tid];
    const float l1 = logits[b * Kc + tid + 256];
    wlds[tid]       = EXP2F((l0 - 0.5f * m2buf[tid])       * LOG2E);
    wlds[tid + 256] = EXP2F((l1 - 0.5f * m2buf[tid + 256]) * LOG2E);

    float mx = fmaxf(l0, l1);
    #pragma unroll
    for (int off = 32; off >= 1; off >>= 1) mx = fmaxf(mx, __shfl_xor(mx, off));
    if (lane == 0) red[wid] = mx;

    // x A-fragments direct from global; convert (x*log2e) -> e4m3 in-register
    const int row0 = rw + ln, row1 = row0 + 16;
    const float4* xp0 = (const float4*)(x + ((size_t)b * Sc + s0 + row0) * Dc) + q * 2;
    const float4* xp1 = (const float4*)(x + ((size_t)b * Sc + s0 + row1) * Dc) + q * 2;
    float4 v0 = xp0[0], v1 = xp0[1];
    float4 u0 = xp1[0], u1 = xp1[1];

    int2 A0, A1;
    A0.x = pkfp8<false>(v0.x * LOG2E, v0.y * LOG2E, 0);
    A0.x = pkfp8<true >(v0.z * LOG2E, v0.w * LOG2E, A0.x);
    A0.y = pkfp8<false>(v1.x * LOG2E, v1.y * LOG2E, 0);
    A0.y = pkfp8<true >(v1.z * LOG2E, v1.w * LOG2E, A0.y);
    A1.x = pkfp8<false>(u0.x * LOG2E, u0.y * LOG2E, 0);
    A1.x = pkfp8<true >(u0.z * LOG2E, u0.w * LOG2E, A1.x);
    A1.y = pkfp8<false>(u1.x * LOG2E, u1.y * LOG2E, 0);
    A1.y = pkfp8<true >(u1.z * LOG2E, u1.w * LOG2E, A1.y);
    const long a0 = *(const long*)&A0;
    const long a1 = *(const long*)&A1;

    float p0 = v0.x*v0.x + v0.y*v0.y + v0.z*v0.z + v0.w*v0.w
             + v1.x*v1.x + v1.y*v1.y + v1.z*v1.z + v1.w*v1.w;
    float p1 = u0.x*u0.x + u0.y*u0.y + u0.z*u0.z + u0.w*u0.w
             + u1.x*u1.x + u1.y*u1.y + u1.z*u1.z + u1.w*u1.w;
    p0 += __shfl_xor(p0, 16); p0 += __shfl_xor(p0, 32);
    p1 += __shfl_xor(p1, 16); p1 += __shfl_xor(p1, 32);
    if (q == 0) { x2p[row0] = p0; x2p[row1] = p1; }
    __syncthreads();

    // finish lse (max across waves parked in red[0..3])
    const float mxb = fmaxf(fmaxf(red[0], red[1]), fmaxf(red[2], red[3]));
    float sm = EXP2F((l0 - mxb) * LOG2E) + EXP2F((l1 - mxb) * LOG2E);
    #pragma unroll
    for (int off = 32; off >= 1; off >>= 1) sm += __shfl_xor(sm, off);
    if (lane == 0) red[4 + wid] = sm;

    const f32x4 zero = {0.f, 0.f, 0.f, 0.f};
    float acc0[4] = {0.f, 0.f, 0.f, 0.f};
    float acc1[4] = {0.f, 0.f, 0.f, 0.f};

    #pragma unroll 4
    for (int kt = 0; kt < 32; ++kt) {
        const int krow = kt * 16 + ln;
        const long  bfr = *(const long*)&mlds[swz8(krow, q)];
        const float wv  = wlds[krow];         // 16 consecutive floats, bcast over q
        f32x4 d0 = __builtin_amdgcn_mfma_f32_16x16x32_fp8_fp8(a0, bfr, zero, 0, 0, 0);
        f32x4 d1 = __builtin_amdgcn_mfma_f32_16x16x32_fp8_fp8(a1, bfr, zero, 0, 0, 0);
        #pragma unroll
        for (int r = 0; r < 4; ++r) {
            acc0[r] = fmaf(wv, EXP2F(d0[r]), acc0[r]);
            acc1[r] = fmaf(wv, EXP2F(d1[r]), acc1[r]);
        }
    }
    __syncthreads();                          // red[4..7] ready
    const float lse  = mxb + LN2 * LOG2F(red[4] + red[5] + red[6] + red[7]);
    const float base = LOG_NORM + lse;

    // reduce over the 16 k-columns (low-4 lane bits), then write
    #pragma unroll
    for (int r = 0; r < 4; ++r) {
        float s0v = acc0[r], s1v = acc1[r];
        s0v += __shfl_xor(s0v, 1); s0v += __shfl_xor(s0v, 2);
        s0v += __shfl_xor(s0v, 4); s0v += __shfl_xor(s0v, 8);
        s1v += __shfl_xor(s1v, 1); s1v += __shfl_xor(s1v, 2);
        s1v += __shfl_xor(s1v, 4); s1v += __shfl_xor(s1v, 8);
        if (ln == 0) {
            const int r0 = rw + q * 4 + r;       // C/D row = quad*4 + reg
            const int r1 = r0 + 16;
            out[(size_t)b * Sc + s0 + r0] = 0.5f * x2p[r0] + base - LN2 * LOG2F(s0v);
            out[(size_t)b * Sc + s0 + r1] = 0.5f * x2p[r1] + base - LN2 * LOG2F(s1v);
        }
    }
}

extern "C" void kernel_launch(void* const* d_in, const int* in_sizes, int n_in,
                              void* d_out, int out_size, void* d_ws, size_t ws_size,
                              hipStream_t stream) {
    const float* x      = (const float*)d_in[0];
    const float* logits = (const float*)d_in[1];
    const float* means  = (const float*)d_in[2];
    float* out = (float*)d_out;
    (void)in_sizes; (void)n_in; (void)out_size; (void)ws_size;

    unsigned short* mf8   = (unsigned short*)d_ws;             // 16 KB (8192 u16)
    float*          m2buf = (float*)((char*)d_ws + 16384);     //  2 KB

    hipLaunchKernelGGL(gm_m2f8, dim3(32), dim3(256), 0, stream, means, mf8, m2buf);
    hipLaunchKernelGGL(gm_main, dim3(Bc * (Sc / ST)), dim3(256), 0, stream,
                       x, logits, m2buf, mf8, out);
}